// Round 12
// baseline (116.776 us; speedup 1.0000x reference)
//
#include <hip/hip_runtime.h>
#include <hip/hip_bf16.h>
#include <stdint.h>

// CostVolumeAttention2: B=2, N=8192, C=512, heads=8, hd=64, T=8, H=W=32, U=49.
// Linearized softmax: |M|<=49/64^2=0.012 -> exp(M)=1+M to 7e-5 rel accuracy.
// attn @ v collapses to rank-50:  num = A'^T (A' v),  den = A'^T (A' 1),
// where A' = corr with a ones-row (slot u'=63), u' = dy*8+dx (pad slots zero).
// R12: k_corr single-drain (v staged upfront into dedicated vbuf; second
// drain+barrier removed); GEMMs at launch_bounds(256,4) for 4 blocks/CU.

#define DEVFN __device__ __forceinline__

typedef __attribute__((ext_vector_type(8))) short bf16x8;
typedef __attribute__((ext_vector_type(4))) short s16x4;
typedef __attribute__((ext_vector_type(4))) float f32x4;

DEVFN float bf2f(short s) {
  union { unsigned int u; float f; } v;
  v.u = ((unsigned int)(unsigned short)s) << 16;
  return v.f;
}
DEVFN short f2bf(float f) {
  __hip_bfloat16 h = __float2bfloat16(f);
  return *reinterpret_cast<short*>(&h);
}

DEVFN void gl_lds16(const void* g, void* l) {
  __builtin_amdgcn_global_load_lds((const __attribute__((address_space(1))) void*)g,
                                   (__attribute__((address_space(3))) void*)l, 16, 0, 0);
}

#define MFMA(a, b, c) __builtin_amdgcn_mfma_f32_16x16x32_bf16((a), (b), (c), 0, 0, 0)

#define NTOK 8192
#define HW   1024

// ------------------------------------------- fp32->bf16, 3 buffers, 1 launch
__global__ void k_cvt3(const float* __restrict__ x, const float* __restrict__ wq,
                       const float* __restrict__ wp, short* __restrict__ xb,
                       short* __restrict__ wqb, short* __restrict__ wpb) {
  int pid = blockIdx.x;
  const float* in; short* out; int i;
  if (pid < 4096)      { in = x;  out = xb;  i = pid * 256 + threadIdx.x; }
  else if (pid < 4480) { in = wq; out = wqb; i = (pid - 4096) * 256 + threadIdx.x; }
  else                 { in = wp; out = wpb; i = (pid - 4480) * 256 + threadIdx.x; }
  const float4* p = (const float4*)in + (size_t)i * 2;
  float4 a = p[0], b = p[1];
  bf16x8 r;
  r[0]=f2bf(a.x); r[1]=f2bf(a.y); r[2]=f2bf(a.z); r[3]=f2bf(a.w);
  r[4]=f2bf(b.x); r[5]=f2bf(b.y); r[6]=f2bf(b.z); r[7]=f2bf(b.w);
  *(bf16x8*)(out + (size_t)i * 8) = r;
}

// --------------------------------------- qkv GEMM: qkvb = xb(bf16) @ wqkv^T
// Both operands via global_load_lds. M=16384 N=1536 K=512. XCD m-panel decode.
// q/k cols (<1024) L2-normalized per-head in epilogue.
__global__ __launch_bounds__(256, 4) void k_gemm_qkv(
    const short* __restrict__ A, const short* __restrict__ Bm, short* __restrict__ Cp)
{
  __shared__ short lA[128 * 64];
  __shared__ short lB[128 * 64];
  const int tid = threadIdx.x;
  const int lane = tid & 63, w = tid >> 6;
  const int wm = w >> 1, wn = w & 1;
  const int r15 = lane & 15, hi = (lane >> 4) * 16, g4 = (lane >> 4) * 4;
  const int pid = blockIdx.x;
  const int m0 = ((pid & 7) * 16 + ((pid >> 3) & 15)) * 128;
  const int n0 = (pid >> 7) * 128;

  f32x4 acc[4][4];
#pragma unroll
  for (int i = 0; i < 4; i++)
#pragma unroll
    for (int j = 0; j < 4; j++) acc[i][j] = (f32x4)0.f;

  for (int k0 = 0; k0 < 512; k0 += 64) {
#pragma unroll
    for (int it = 0; it < 4; it++) {
      int chunk = it * 256 + tid;
      int row = chunk >> 3;
      int sb = ((chunk & 7) * 16) ^ ((row & 7) << 4);
      gl_lds16((const char*)(A + (size_t)(m0 + row) * 512 + k0) + sb, lA + (it * 256 + w * 64) * 8);
      gl_lds16((const char*)(Bm + (size_t)(n0 + row) * 512 + k0) + sb, lB + (it * 256 + w * 64) * 8);
    }
    asm volatile("s_waitcnt vmcnt(0)" ::: "memory");
    __syncthreads();

    bf16x8 af[4][2], bfr[4][2];
#pragma unroll
    for (int mt = 0; mt < 4; mt++) {
      int row = wm * 64 + mt * 16 + r15;
#pragma unroll
      for (int kh = 0; kh < 2; kh++) {
        int off = row * 128 + ((kh * 64 + hi) ^ ((row & 7) << 4));
        af[mt][kh] = *(const bf16x8*)((const char*)lA + off);
      }
    }
#pragma unroll
    for (int nt = 0; nt < 4; nt++) {
      int row = wn * 64 + nt * 16 + r15;
#pragma unroll
      for (int kh = 0; kh < 2; kh++) {
        int off = row * 128 + ((kh * 64 + hi) ^ ((row & 7) << 4));
        bfr[nt][kh] = *(const bf16x8*)((const char*)lB + off);
      }
    }
#pragma unroll
    for (int mt = 0; mt < 4; mt++)
#pragma unroll
      for (int nt = 0; nt < 4; nt++) {
        acc[mt][nt] = MFMA(af[mt][0], bfr[nt][0], acc[mt][nt]);
        acc[mt][nt] = MFMA(af[mt][1], bfr[nt][1], acc[mt][nt]);
      }
    __syncthreads();
  }

  if (n0 < 1024) {  // q/k: normalize each row's 64-col head vector
#pragma unroll
    for (int mt = 0; mt < 4; mt++)
#pragma unroll
      for (int j = 0; j < 4; j++) {
        float ss = 0.f;
#pragma unroll
        for (int nt = 0; nt < 4; nt++) ss += acc[mt][nt][j] * acc[mt][nt][j];
        ss += __shfl_xor(ss, 1); ss += __shfl_xor(ss, 2);
        ss += __shfl_xor(ss, 4); ss += __shfl_xor(ss, 8);
        float sc = 1.f / (8.f * fmaxf(sqrtf(ss), 1e-12f));
#pragma unroll
        for (int nt = 0; nt < 4; nt++) acc[mt][nt][j] *= sc;
      }
  }

#pragma unroll
  for (int mt = 0; mt < 4; mt++)
#pragma unroll
    for (int j = 0; j < 4; j++) {
      int row = m0 + wm * 64 + mt * 16 + g4 + j;
#pragma unroll
      for (int nt = 0; nt < 4; nt++) {
        int col = n0 + wn * 64 + nt * 16 + r15;
        Cp[(size_t)row * 1536 + col] = f2bf(acc[mt][nt][j]);
      }
    }
}

// ------------------------------------------------- proj GEMM: C = A * B^T + bias
__global__ __launch_bounds__(256, 4) void k_gemm_proj(
    const short* __restrict__ A, const short* __restrict__ Bm,
    float* __restrict__ Cp, const float* __restrict__ bias)
{
  __shared__ short lA[128 * 64];
  __shared__ short lB[128 * 64];
  const int tid = threadIdx.x;
  const int lane = tid & 63, w = tid >> 6;
  const int wm = w >> 1, wn = w & 1;
  const int r15 = lane & 15, hi = (lane >> 4) * 16, g4 = (lane >> 4) * 4;
  const int pid = blockIdx.x;
  const int m0 = ((pid & 7) * 16 + ((pid >> 3) & 15)) * 128;
  const int n0 = (pid >> 7) * 128;

  f32x4 acc[4][4];
#pragma unroll
  for (int i = 0; i < 4; i++)
#pragma unroll
    for (int j = 0; j < 4; j++) acc[i][j] = (f32x4)0.f;

  for (int k0 = 0; k0 < 512; k0 += 64) {
#pragma unroll
    for (int it = 0; it < 4; it++) {
      int chunk = it * 256 + tid;
      int row = chunk >> 3;
      int sb = ((chunk & 7) * 16) ^ ((row & 7) << 4);
      gl_lds16((const char*)(A + (size_t)(m0 + row) * 512 + k0) + sb, lA + (it * 256 + w * 64) * 8);
      gl_lds16((const char*)(Bm + (size_t)(n0 + row) * 512 + k0) + sb, lB + (it * 256 + w * 64) * 8);
    }
    asm volatile("s_waitcnt vmcnt(0)" ::: "memory");
    __syncthreads();

    bf16x8 af[4][2], bfr[4][2];
#pragma unroll
    for (int mt = 0; mt < 4; mt++) {
      int row = wm * 64 + mt * 16 + r15;
#pragma unroll
      for (int kh = 0; kh < 2; kh++) {
        int off = row * 128 + ((kh * 64 + hi) ^ ((row & 7) << 4));
        af[mt][kh] = *(const bf16x8*)((const char*)lA + off);
      }
    }
#pragma unroll
    for (int nt = 0; nt < 4; nt++) {
      int row = wn * 64 + nt * 16 + r15;
#pragma unroll
      for (int kh = 0; kh < 2; kh++) {
        int off = row * 128 + ((kh * 64 + hi) ^ ((row & 7) << 4));
        bfr[nt][kh] = *(const bf16x8*)((const char*)lB + off);
      }
    }
#pragma unroll
    for (int mt = 0; mt < 4; mt++)
#pragma unroll
      for (int nt = 0; nt < 4; nt++) {
        acc[mt][nt] = MFMA(af[mt][0], bfr[nt][0], acc[mt][nt]);
        acc[mt][nt] = MFMA(af[mt][1], bfr[nt][1], acc[mt][nt]);
      }
    __syncthreads();
  }

#pragma unroll
  for (int mt = 0; mt < 4; mt++)
#pragma unroll
    for (int j = 0; j < 4; j++) {
      int row = m0 + wm * 64 + mt * 16 + g4 + j;
#pragma unroll
      for (int nt = 0; nt < 4; nt++) {
        int col = n0 + wn * 64 + nt * 16 + r15;
        Cp[(size_t)row * 512 + col] = acc[mt][nt][j] + bias[col];
      }
    }
}

// ---------------------------------------------------------------- cost volume
// Single-drain v4: 2048 blocks x 512 threads; block = (bht, y-pair). Stage
// q(2 rows) + k(8-row window) + v(64 rows of 64-d) = 56KB in ONE burst with
// ONE vmcnt drain. Per y: waves 0-6 MFMA 28 Gram tiles -> scr; waves split
// gather corrI/corrU (coalesced b128). Tail: transpose vbuf -> vT (no drain).
__global__ __launch_bounds__(512, 2) void k_corr(
    const short* __restrict__ qkvb, short* __restrict__ corrI,
    short* __restrict__ corrU, short* __restrict__ vT)
{
  __shared__ short stg[2560 * 8];   // 40KB: rows 0-63 q (y0,y0+1), 64-319 k slots
  __shared__ short vbuf[512 * 8];   // 8KB: v rows [i][d] linear
  __shared__ short scr[28 * 256];   // 14KB: corr tiles

  const int tid = threadIdx.x;
  const int lane = tid & 63, w = tid >> 6;
  const int r15 = lane & 15, hi = (lane >> 4) * 16, g4 = (lane >> 4) * 4;
  const int pid = blockIdx.x;
  const int xcd = pid & 7, idx = pid >> 3;       // idx 0..255
  const int g = 2 * xcd + (idx & 1);
  const int head = (idx >> 1) & 7;
  const int y0 = (idx >> 4) * 2;                 // 0,2,..,30
  const int b = g >> 3, tf = g & 7;
  const int bht = b * 64 + head * 8 + tf;
  const int tk = (tf < 7) ? tf + 1 : 7;
  const size_t qbase = ((size_t)(g * HW)) * 1536 + head * 64;
  const size_t kbase = ((size_t)((b * 8 + tk) * HW)) * 1536 + 512 + head * 64;

  // ---- stage q+k (5 chunks/thread) and v (1 chunk/thread); ONE drain
#pragma unroll
  for (int i = 0; i < 5; i++) {
    int c = i * 512 + tid;
    int row = c >> 3;
    int sb = ((c & 7) * 16) ^ ((row & 7) << 4);
    short* dst = stg + (i * 512 + w * 64) * 8;   // wave-uniform base
    if (i == 0) {  // q: rows y0, y0+1
      int j = c >> 8, px = (c >> 3) & 31;
      gl_lds16((const char*)(qkvb + qbase + (size_t)((y0 + j) * 32 + px) * 1536) + sb, dst);
    } else {       // k: slots 0..7 -> rows y0-3 .. y0+4
      int c2 = c - 512;
      int slot = c2 >> 8, px = (c2 >> 3) & 31;
      int r = y0 - 3 + slot;
      if (r >= 0 && r < 32)
        gl_lds16((const char*)(qkvb + kbase + (size_t)(r * 32 + px) * 1536) + sb, dst);
      else
        *(bf16x8*)(stg + (size_t)c * 8) = (bf16x8)(short)0;
    }
  }
  { // v: 512 chunks, 1/thread, linear [i][64]
    int i = tid >> 3;
    gl_lds16((const char*)(qkvb + ((size_t)(g * HW + y0 * 32 + i)) * 1536 + 1024 + head * 64)
                 + (tid & 7) * 16,
             vbuf + (w * 64) * 8);
  }
  asm volatile("s_waitcnt vmcnt(0)" ::: "memory");
  __syncthreads();

#pragma unroll 1
  for (int j = 0; j < 2; j++) {
    const int y = y0 + j;
    if (w < 7) {
      bf16x8 aq[2][2];
#pragma unroll
      for (int mt = 0; mt < 2; mt++) {
        int row = j * 32 + mt * 16 + r15;
#pragma unroll
        for (int kh = 0; kh < 2; kh++) {
          int off = row * 128 + ((kh * 64 + hi) ^ ((row & 7) << 4));
          aq[mt][kh] = *(const bf16x8*)((const char*)stg + off);
        }
      }
#pragma unroll
      for (int c = 0; c < 4; c++) {
        int t = w * 4 + c, nt = t >> 1, mt = t & 1;
        int dy = nt >> 1, xh = nt & 1;
        int slot = dy + j;
        int xx = xh * 16 + r15;
        int rowB = 64 + slot * 32 + xx;
        f32x4 a = (f32x4)0.f;
#pragma unroll
        for (int kh = 0; kh < 2; kh++) {
          int off = rowB * 128 + ((kh * 64 + hi) ^ ((rowB & 7) << 4));
          bf16x8 bb = *(const bf16x8*)((const char*)stg + off);
          a = MFMA(aq[mt][kh], bb, a);
        }
        s16x4 pk;
        pk[0] = f2bf(a[0]); pk[1] = f2bf(a[1]); pk[2] = f2bf(a[2]); pk[3] = f2bf(a[3]);
        *(s16x4*)(scr + t * 256 + r15 * 16 + g4) = pk;   // [p=r15][x=g4..g4+3]
      }
    }
    __syncthreads();

    if (tid < 256) {  // gather corrI: (x, u-octet)
      int x = tid >> 3, u0 = (tid & 7) * 8;
      bf16x8 o;
#pragma unroll
      for (int e = 0; e < 8; e++) {
        int u = u0 + e;
        int dy = u >> 3, dx = u & 7;
        int xx = x + dx - 3;
        int dyc = (dy > 6) ? 6 : dy;
        int t2 = (dyc * 2 + ((xx & 31) >> 4)) * 2 + (x >> 4);
        short vv = scr[t2 * 256 + (xx & 15) * 16 + (x & 15)];
        bool ok = (dx < 7) && (dy < 7) && (xx >= 0) && (xx < 32);
        short res = ok ? vv : (short)0;
        o[e] = (u == 63) ? (short)0x3F80 : res;
      }
      *(bf16x8*)(corrI + ((size_t)bht * HW + y * 32 + x) * 64 + u0) = o;
    } else {          // gather corrU: (u, x-octet)
      int tt = tid - 256;
      int u = tt >> 2, x0 = (tt & 3) * 8;
      int dy = u >> 3, dx = u & 7;
      int dyc = (dy > 6) ? 6 : dy;
      bf16x8 o;
#pragma unroll
      for (int e = 0; e < 8; e++) {
        int x = x0 + e;
        int xx = x + dx - 3;
        int t2 = (dyc * 2 + ((xx & 31) >> 4)) * 2 + (x >> 4);
        short vv = scr[t2 * 256 + (xx & 15) * 16 + (x & 15)];
        bool ok = (dx < 7) && (dy < 7) && (xx >= 0) && (xx < 32);
        short res = ok ? vv : (short)0;
        o[e] = (u == 63) ? (short)0x3F80 : res;
      }
      *(bf16x8*)(corrU + (size_t)bht * 65536 + u * HW + y * 32 + x0) = o;
    }
    __syncthreads();   // scr reused next y
  }

  // ---- vT: transpose vbuf (written before first barrier; already synced)
  {
    int d = tid >> 3, i0w = (tid & 7) * 8;
    bf16x8 o;
#pragma unroll
    for (int e = 0; e < 8; e++) o[e] = vbuf[(i0w + e) * 64 + d];
    *(bf16x8*)(vT + ((size_t)bht * 64 + d) * HW + y0 * 32 + i0w) = o;
  }
}

// --------------------------------- fused rank-50 attention, d-split x2
__global__ __launch_bounds__(256, 2) void k_attn(
    const short* __restrict__ corrU, const short* __restrict__ corrI,
    const short* __restrict__ vT, short* __restrict__ out_attn)
{
  __shared__ short lV[32 * 64];
  __shared__ short lU[64 * 64];
  __shared__ short GTl[32 * 72];
  __shared__ float cl[64];
  __shared__ float cpart[256];
  const int tid = threadIdx.x, lane = tid & 63, w = tid >> 6;
  const int r15 = lane & 15, hi = (lane >> 4) * 16, g4 = (lane >> 4) * 4, g8 = (lane >> 4) * 8;
  const int pid = blockIdx.x;
  const int xcd = pid & 7, idx = pid >> 3;   // 0..31
  const int g = 2 * xcd + (idx & 1);
  const int head = (idx >> 1) & 7;
  const int dh = (idx >> 4) & 1;
  const int b = g >> 3, tf = g & 7;
  const int bht = b * 64 + head * 8 + tf;
  const int wm = w & 1, wn2 = (w >> 1) * 2;

  f32x4 accP[2];
  accP[0] = (f32x4)0.f; accP[1] = (f32x4)0.f;
  float c1p = 0.f;
  const short* vbase = vT + ((size_t)bht * 64 + dh * 32) * HW;
  const short* ubase = corrU + (size_t)bht * 65536;

  for (int i0 = 0; i0 < 1024; i0 += 64) {
    { int row = tid >> 3;
      int sb = ((tid & 7) * 16) ^ ((row & 7) << 4);
      gl_lds16((const char*)(vbase + (size_t)row * HW + i0) + sb, lV + (w * 64) * 8);
    }
#pragma unroll
    for (int it = 0; it < 2; it++) {
      int chunk = it * 256 + tid;
      int row = chunk >> 3;
      int sb = ((chunk & 7) * 16) ^ ((row & 7) << 4);
      gl_lds16((const char*)(ubase + (size_t)row * HW + i0) + sb, lU + (it * 256 + w * 64) * 8);
    }
    asm volatile("s_waitcnt vmcnt(0)" ::: "memory");
    __syncthreads();
    bf16x8 av[2];
    int rowA = wm * 16 + r15;
#pragma unroll
    for (int kh = 0; kh < 2; kh++) {
      int off = rowA * 128 + ((kh * 64 + hi) ^ ((rowA & 7) << 4));
      av[kh] = *(const bf16x8*)((const char*)lV + off);
    }
#pragma unroll
    for (int c = 0; c < 2; c++) {
      int rowB = (wn2 + c) * 16 + r15;
#pragma unroll
      for (int kh = 0; kh < 2; kh++) {
        int off = rowB * 128 + ((kh * 64 + hi) ^ ((rowB & 7) << 4));
        bf16x8 bu = *(const bf16x8*)((const char*)lU + off);
        accP[c] = MFMA(av[kh], bu, accP[c]);
      }
    }
    { int u = tid >> 2, partc = tid & 3;
#pragma unroll
      for (int h = 0; h < 2; h++) {
        int off = u * 128 + ((partc * 32 + h * 16) ^ ((u & 7) << 4));
        bf16x8 vv = *(const bf16x8*)((const char*)lU + off);
#pragma unroll
        for (int e = 0; e < 8; e++) c1p += bf2f(vv[e]);
      }
    }
    __syncthreads();
  }
  cpart[tid] = c1p;
#pragma unroll
  for (int c = 0; c < 2; c++)
#pragma unroll
    for (int j = 0; j < 4; j++) {
      int d = wm * 16 + g4 + j, u = (wn2 + c) * 16 + r15;
      GTl[d * 72 + u] = f2bf(accP[c][j]);
    }
  __syncthreads();
  if (tid < 64) cl[tid] = cpart[4 * tid] + cpart[4 * tid + 1] + cpart[4 * tid + 2] + cpart[4 * tid + 3];
  __syncthreads();

  bf16x8 gtb[2][2];
#pragma unroll
  for (int nt = 0; nt < 2; nt++)
#pragma unroll
    for (int kh = 0; kh < 2; kh++)
      gtb[nt][kh] = *(const bf16x8*)((const char*)GTl + (nt * 16 + r15) * 144 + kh * 64 + hi);

  float c1r[2][8];
#pragma unroll
  for (int kh = 0; kh < 2; kh++)
#pragma unroll
    for (int e = 0; e < 8; e++) c1r[kh][e] = cl[kh * 32 + g8 + e];

  const short* ibase = corrI + (size_t)bht * HW * 64;
  for (int s = 0; s < 16; s++) {
    int i0 = w * 256 + s * 16;
    bf16x8 af[2];
#pragma unroll
    for (int kh = 0; kh < 2; kh++)
      af[kh] = *(const bf16x8*)(ibase + (size_t)(i0 + r15) * 64 + kh * 32 + g8);
    f32x4 a2[2];
    a2[0] = (f32x4)0.f; a2[1] = (f32x4)0.f;
#pragma unroll
    for (int nt = 0; nt < 2; nt++)
#pragma unroll
      for (int kh = 0; kh < 2; kh++) a2[nt] = MFMA(af[kh], gtb[nt][kh], a2[nt]);

    float dp = 0.f;
#pragma unroll
    for (int kh = 0; kh < 2; kh++)
#pragma unroll
      for (int e = 0; e < 8; e++) dp += bf2f(af[kh][e]) * c1r[kh][e];
    dp += __shfl_xor(dp, 16);
    dp += __shfl_xor(dp, 32);

#pragma unroll
    for (int j = 0; j < 4; j++) {
      float dj = __shfl(dp, g4 + j);
      float inv = 1.f / dj;
      int i = i0 + g4 + j;
      size_t outrow = ((size_t)(g * HW + i)) * 512 + head * 64 + dh * 32;
#pragma unroll
      for (int nt = 0; nt < 2; nt++)
        out_attn[outrow + nt * 16 + r15] = f2bf(a2[nt][j] * inv);
    }
  }
}

extern "C" void kernel_launch(void* const* d_in, const int* in_sizes, int n_in,
                              void* d_out, int out_size, void* d_ws, size_t ws_size,
                              hipStream_t stream) {
  (void)in_sizes; (void)n_in; (void)out_size; (void)ws_size;
  const float* x      = (const float*)d_in[0];
  const float* w_qkv  = (const float*)d_in[1];
  const float* w_proj = (const float*)d_in[2];
  const float* b_proj = (const float*)d_in[3];

  char* ws = (char*)d_ws;
  short* qkvb   = (short*)(ws);                 // 50,331,648 B [16384][1536]
  short* xb     = (short*)(ws + 50331648);      // 16,777,216 B
  short* corrU  = (short*)(ws + 67108864);      // 16,777,216 B [128][64][1024]
  short* vT     = (short*)(ws + 83886080);      // 16,777,216 B [128][64][1024]
  short* wqkvb  = (short*)(ws + 100663296);     //  1,572,864 B
  short* wprojb = (short*)(ws + 102236160);     //    524,288 B
  short* corrI    = xb;    // alias: xb dead after qkv GEMM
  short* out_attn = qkvb;  // alias: qkvb dead after corr (incl. vT epilogue)

  k_cvt3<<<dim3(4608), 256, 0, stream>>>(x, w_qkv, w_proj, xb, wqkvb, wprojb);

  k_gemm_qkv<<<dim3(1536), 256, 0, stream>>>(xb, wqkvb, qkvb);

  k_corr<<<dim3(2048), 512, 0, stream>>>(qkvb, corrI, corrU, vT);

  k_attn<<<dim3(256), 256, 0, stream>>>(corrU, corrI, vT, out_attn);

  k_gemm_proj<<<dim3(512), 256, 0, stream>>>(out_attn, wprojb, (float*)d_out, b_proj);
}

// Round 13
// 111.877 us; speedup vs baseline: 1.0438x; 1.0438x over previous
//
#include <hip/hip_runtime.h>
#include <hip/hip_bf16.h>
#include <stdint.h>

// CostVolumeAttention2: B=2, N=8192, C=512, heads=8, hd=64, T=8, H=W=32, U=49.
// Linearized softmax: |M|<=49/64^2=0.012 -> exp(M)=1+M to 7e-5 rel accuracy.
// attn @ v collapses to rank-50:  num = A'^T (A' v),  den = A'^T (A' 1),
// where A' = corr with a ones-row (slot u'=63), u' = dy*8+dx (pad slots zero).
// R13 = exact revert to R8 (best measured: 111.5us). q/k L2-norm fused into
// the qkv GEMM epilogue; vT production fused into k_corr; GEMMs (256,2);
// k_corr (512,4) two-drain. 5 kernels.

#define DEVFN __device__ __forceinline__

typedef __attribute__((ext_vector_type(8))) short bf16x8;
typedef __attribute__((ext_vector_type(4))) short s16x4;
typedef __attribute__((ext_vector_type(4))) float f32x4;

DEVFN float bf2f(short s) {
  union { unsigned int u; float f; } v;
  v.u = ((unsigned int)(unsigned short)s) << 16;
  return v.f;
}
DEVFN short f2bf(float f) {
  __hip_bfloat16 h = __float2bfloat16(f);
  return *reinterpret_cast<short*>(&h);
}

DEVFN void gl_lds16(const void* g, void* l) {
  __builtin_amdgcn_global_load_lds((const __attribute__((address_space(1))) void*)g,
                                   (__attribute__((address_space(3))) void*)l, 16, 0, 0);
}

#define MFMA(a, b, c) __builtin_amdgcn_mfma_f32_16x16x32_bf16((a), (b), (c), 0, 0, 0)

#define NTOK 8192
#define HW   1024

// ------------------------------------------- fp32->bf16, 3 buffers, 1 launch
__global__ void k_cvt3(const float* __restrict__ x, const float* __restrict__ wq,
                       const float* __restrict__ wp, short* __restrict__ xb,
                       short* __restrict__ wqb, short* __restrict__ wpb) {
  int pid = blockIdx.x;
  const float* in; short* out; int i;
  if (pid < 4096)      { in = x;  out = xb;  i = pid * 256 + threadIdx.x; }
  else if (pid < 4480) { in = wq; out = wqb; i = (pid - 4096) * 256 + threadIdx.x; }
  else                 { in = wp; out = wpb; i = (pid - 4480) * 256 + threadIdx.x; }
  const float4* p = (const float4*)in + (size_t)i * 2;
  float4 a = p[0], b = p[1];
  bf16x8 r;
  r[0]=f2bf(a.x); r[1]=f2bf(a.y); r[2]=f2bf(a.z); r[3]=f2bf(a.w);
  r[4]=f2bf(b.x); r[5]=f2bf(b.y); r[6]=f2bf(b.z); r[7]=f2bf(b.w);
  *(bf16x8*)(out + (size_t)i * 8) = r;
}

// ------------------------------------------------- GEMM: C[M][N] = A * B^T
// 1D grid = 128*nblocks; XCD x owns m-panels [x*16,(x+1)*16).
// F32OUT==0 (qkv): cols < 1024 (q,k slices) are L2-normalized per 64-col head
// vector in the epilogue (wave owns exactly cols [n0+wn*64, +64)).
template<int F32OUT>
__global__ __launch_bounds__(256, 2) void k_gemm_bt(
    const short* __restrict__ A, const short* __restrict__ Bm,
    void* __restrict__ Cp, const float* __restrict__ bias, int M, int N, int K)
{
  __shared__ short lA[128 * 64];
  __shared__ short lB[128 * 64];
  const int tid = threadIdx.x;
  const int lane = tid & 63, w = tid >> 6;
  const int wm = w >> 1, wn = w & 1;
  const int r15 = lane & 15, hi = (lane >> 4) * 16, g4 = (lane >> 4) * 4;
  const int pid = blockIdx.x;
  const int m0 = ((pid & 7) * 16 + ((pid >> 3) & 15)) * 128;
  const int n0 = (pid >> 7) * 128;

  f32x4 acc[4][4];
#pragma unroll
  for (int i = 0; i < 4; i++)
#pragma unroll
    for (int j = 0; j < 4; j++) acc[i][j] = (f32x4)0.f;

  for (int k0 = 0; k0 < K; k0 += 64) {
#pragma unroll
    for (int it = 0; it < 4; it++) {
      int chunk = it * 256 + tid;
      int row = chunk >> 3;
      int sb = ((chunk & 7) * 16) ^ ((row & 7) << 4);
      const char* srcA = (const char*)(A + (size_t)(m0 + row) * K + k0) + sb;
      const char* srcB = (const char*)(Bm + (size_t)(n0 + row) * K + k0) + sb;
      gl_lds16(srcA, lA + (it * 256 + w * 64) * 8);
      gl_lds16(srcB, lB + (it * 256 + w * 64) * 8);
    }
    asm volatile("s_waitcnt vmcnt(0)" ::: "memory");
    __syncthreads();

    bf16x8 af[4][2], bfr[4][2];
#pragma unroll
    for (int mt = 0; mt < 4; mt++) {
      int row = wm * 64 + mt * 16 + r15;
#pragma unroll
      for (int kh = 0; kh < 2; kh++) {
        int off = row * 128 + ((kh * 64 + hi) ^ ((row & 7) << 4));
        af[mt][kh] = *(const bf16x8*)((const char*)lA + off);
      }
    }
#pragma unroll
    for (int nt = 0; nt < 4; nt++) {
      int row = wn * 64 + nt * 16 + r15;
#pragma unroll
      for (int kh = 0; kh < 2; kh++) {
        int off = row * 128 + ((kh * 64 + hi) ^ ((row & 7) << 4));
        bfr[nt][kh] = *(const bf16x8*)((const char*)lB + off);
      }
    }
#pragma unroll
    for (int mt = 0; mt < 4; mt++)
#pragma unroll
      for (int nt = 0; nt < 4; nt++) {
        acc[mt][nt] = MFMA(af[mt][0], bfr[nt][0], acc[mt][nt]);
        acc[mt][nt] = MFMA(af[mt][1], bfr[nt][1], acc[mt][nt]);
      }
    __syncthreads();
  }

  if (F32OUT == 0 && n0 < 1024) {
    // normalize each row's 64-col head vector: wave holds it in acc[mt][*][j]
#pragma unroll
    for (int mt = 0; mt < 4; mt++)
#pragma unroll
      for (int j = 0; j < 4; j++) {
        float ss = 0.f;
#pragma unroll
        for (int nt = 0; nt < 4; nt++) ss += acc[mt][nt][j] * acc[mt][nt][j];
        ss += __shfl_xor(ss, 1); ss += __shfl_xor(ss, 2);
        ss += __shfl_xor(ss, 4); ss += __shfl_xor(ss, 8);
        float sc = 1.f / (8.f * fmaxf(sqrtf(ss), 1e-12f));
#pragma unroll
        for (int nt = 0; nt < 4; nt++) acc[mt][nt][j] *= sc;
      }
  }

#pragma unroll
  for (int mt = 0; mt < 4; mt++)
#pragma unroll
    for (int j = 0; j < 4; j++) {
      int row = m0 + wm * 64 + mt * 16 + g4 + j;
#pragma unroll
      for (int nt = 0; nt < 4; nt++) {
        int col = n0 + wn * 64 + nt * 16 + r15;
        float v = acc[mt][nt][j];
        if (F32OUT) ((float*)Cp)[(size_t)row * N + col] = v + bias[col];
        else        ((short*)Cp)[(size_t)row * N + col] = f2bf(v);
      }
    }
}

// ---------------------------------------------------------------- cost volume
// v3+vT: 2048 blocks x 512 threads; block = (bht, y-pair). One stage (q 2 rows
// + k 8-row window, 40KB) + one drain. Per y: waves 0-6 MFMA 28 Gram tiles ->
// scr; waves split gather corrI/corrU (coalesced b128). Epilogue: stage the
// block's 64 v-rows (8KB) into scr, transpose, write vT. u'=dy*8+dx, ones @63.
__global__ __launch_bounds__(512, 4) void k_corr(
    const short* __restrict__ qkvb, short* __restrict__ corrI,
    short* __restrict__ corrU, short* __restrict__ vT)
{
  __shared__ short stg[2560 * 8];   // 40KB: rows 0-63 q (y0,y0+1), 64-319 k slots
  __shared__ short scr[28 * 256];   // 14KB: corr tiles; reused for v transpose

  const int tid = threadIdx.x;
  const int lane = tid & 63, w = tid >> 6;
  const int r15 = lane & 15, hi = (lane >> 4) * 16, g4 = (lane >> 4) * 4;
  const int pid = blockIdx.x;
  const int xcd = pid & 7, idx = pid >> 3;       // idx 0..255
  const int g = 2 * xcd + (idx & 1);
  const int head = (idx >> 1) & 7;
  const int y0 = (idx >> 4) * 2;                 // 0,2,..,30
  const int b = g >> 3, tf = g & 7;
  const int bht = b * 64 + head * 8 + tf;
  const int tk = (tf < 7) ? tf + 1 : 7;
  const size_t qbase = ((size_t)(g * HW)) * 1536 + head * 64;
  const size_t kbase = ((size_t)((b * 8 + tk) * HW)) * 1536 + 512 + head * 64;

#pragma unroll
  for (int i = 0; i < 5; i++) {
    int c = i * 512 + tid;
    int row = c >> 3;
    int sb = ((c & 7) * 16) ^ ((row & 7) << 4);
    short* dst = stg + (i * 512 + w * 64) * 8;   // wave-uniform base
    if (i == 0) {  // q: rows y0, y0+1
      int j = c >> 8, px = (c >> 3) & 31;
      gl_lds16((const char*)(qkvb + qbase + (size_t)((y0 + j) * 32 + px) * 1536) + sb, dst);
    } else {       // k: slots 0..7 -> rows y0-3 .. y0+4
      int c2 = c - 512;
      int slot = c2 >> 8, px = (c2 >> 3) & 31;
      int r = y0 - 3 + slot;
      if (r >= 0 && r < 32)
        gl_lds16((const char*)(qkvb + kbase + (size_t)(r * 32 + px) * 1536) + sb, dst);
      else
        *(bf16x8*)(stg + (size_t)c * 8) = (bf16x8)(short)0;
    }
  }
  asm volatile("s_waitcnt vmcnt(0)" ::: "memory");
  __syncthreads();

#pragma unroll 1
  for (int j = 0; j < 2; j++) {
    const int y = y0 + j;
    if (w < 7) {
      bf16x8 aq[2][2];
#pragma unroll
      for (int mt = 0; mt < 2; mt++) {
        int row = j * 32 + mt * 16 + r15;
#pragma unroll
        for (int kh = 0; kh < 2; kh++) {
          int off = row * 128 + ((kh * 64 + hi) ^ ((row & 7) << 4));
          aq[mt][kh] = *(const bf16x8*)((const char*)stg + off);
        }
      }
#pragma unroll
      for (int c = 0; c < 4; c++) {
        int t = w * 4 + c, nt = t >> 1, mt = t & 1;
        int dy = nt >> 1, xh = nt & 1;
        int slot = dy + j;
        int xx = xh * 16 + r15;
        int rowB = 64 + slot * 32 + xx;
        f32x4 a = (f32x4)0.f;
#pragma unroll
        for (int kh = 0; kh < 2; kh++) {
          int off = rowB * 128 + ((kh * 64 + hi) ^ ((rowB & 7) << 4));
          bf16x8 bb = *(const bf16x8*)((const char*)stg + off);
          a = MFMA(aq[mt][kh], bb, a);
        }
        s16x4 pk;
        pk[0] = f2bf(a[0]); pk[1] = f2bf(a[1]); pk[2] = f2bf(a[2]); pk[3] = f2bf(a[3]);
        *(s16x4*)(scr + t * 256 + r15 * 16 + g4) = pk;   // [p=r15][x=g4..g4+3]
      }
    }
    __syncthreads();

    if (tid < 256) {  // gather corrI: (x, u-octet)
      int x = tid >> 3, u0 = (tid & 7) * 8;
      bf16x8 o;
#pragma unroll
      for (int e = 0; e < 8; e++) {
        int u = u0 + e;
        int dy = u >> 3, dx = u & 7;
        int xx = x + dx - 3;
        int dyc = (dy > 6) ? 6 : dy;
        int t2 = (dyc * 2 + ((xx & 31) >> 4)) * 2 + (x >> 4);
        short vv = scr[t2 * 256 + (xx & 15) * 16 + (x & 15)];
        bool ok = (dx < 7) && (dy < 7) && (xx >= 0) && (xx < 32);
        short res = ok ? vv : (short)0;
        o[e] = (u == 63) ? (short)0x3F80 : res;
      }
      *(bf16x8*)(corrI + ((size_t)bht * HW + y * 32 + x) * 64 + u0) = o;
    } else {          // gather corrU: (u, x-octet)
      int tt = tid - 256;
      int u = tt >> 2, x0 = (tt & 3) * 8;
      int dy = u >> 3, dx = u & 7;
      int dyc = (dy > 6) ? 6 : dy;
      bf16x8 o;
#pragma unroll
      for (int e = 0; e < 8; e++) {
        int x = x0 + e;
        int xx = x + dx - 3;
        int t2 = (dyc * 2 + ((xx & 31) >> 4)) * 2 + (x >> 4);
        short vv = scr[t2 * 256 + (xx & 15) * 16 + (x & 15)];
        bool ok = (dx < 7) && (dy < 7) && (xx >= 0) && (xx < 32);
        short res = ok ? vv : (short)0;
        o[e] = (u == 63) ? (short)0x3F80 : res;
      }
      *(bf16x8*)(corrU + (size_t)bht * 65536 + u * HW + y * 32 + x0) = o;
    }
    __syncthreads();   // scr reused (next y / v transpose)
  }

  // ---- vT: stage the block's 64 v rows (linear [i][64], 8KB) and transpose
  {
    int c = tid;                                 // 512 chunks, 1/thread
    int i = c >> 3;
    gl_lds16((const char*)(qkvb + ((size_t)(g * HW + y0 * 32 + i)) * 1536 + 1024 + head * 64)
                 + (c & 7) * 16,
             scr + (w * 64) * 8);                // wave-uniform base, linear
  }
  asm volatile("s_waitcnt vmcnt(0)" ::: "memory");
  __syncthreads();
  {
    int d = tid >> 3, i0w = (tid & 7) * 8;
    bf16x8 o;
#pragma unroll
    for (int e = 0; e < 8; e++) o[e] = scr[(i0w + e) * 64 + d];
    *(bf16x8*)(vT + ((size_t)bht * 64 + d) * HW + y0 * 32 + i0w) = o;
  }
}

// --------------------------------- fused rank-50 attention, d-split x2
__global__ __launch_bounds__(256, 2) void k_attn(
    const short* __restrict__ corrU, const short* __restrict__ corrI,
    const short* __restrict__ vT, short* __restrict__ out_attn)
{
  __shared__ short lV[32 * 64];
  __shared__ short lU[64 * 64];
  __shared__ short GTl[32 * 72];
  __shared__ float cl[64];
  __shared__ float cpart[256];
  const int tid = threadIdx.x, lane = tid & 63, w = tid >> 6;
  const int r15 = lane & 15, hi = (lane >> 4) * 16, g4 = (lane >> 4) * 4, g8 = (lane >> 4) * 8;
  const int pid = blockIdx.x;
  const int xcd = pid & 7, idx = pid >> 3;   // 0..31
  const int g = 2 * xcd + (idx & 1);
  const int head = (idx >> 1) & 7;
  const int dh = (idx >> 4) & 1;
  const int b = g >> 3, tf = g & 7;
  const int bht = b * 64 + head * 8 + tf;
  const int wm = w & 1, wn2 = (w >> 1) * 2;

  f32x4 accP[2];
  accP[0] = (f32x4)0.f; accP[1] = (f32x4)0.f;
  float c1p = 0.f;
  const short* vbase = vT + ((size_t)bht * 64 + dh * 32) * HW;
  const short* ubase = corrU + (size_t)bht * 65536;

  for (int i0 = 0; i0 < 1024; i0 += 64) {
    { int row = tid >> 3;
      int sb = ((tid & 7) * 16) ^ ((row & 7) << 4);
      gl_lds16((const char*)(vbase + (size_t)row * HW + i0) + sb, lV + (w * 64) * 8);
    }
#pragma unroll
    for (int it = 0; it < 2; it++) {
      int chunk = it * 256 + tid;
      int row = chunk >> 3;
      int sb = ((chunk & 7) * 16) ^ ((row & 7) << 4);
      gl_lds16((const char*)(ubase + (size_t)row * HW + i0) + sb, lU + (it * 256 + w * 64) * 8);
    }
    asm volatile("s_waitcnt vmcnt(0)" ::: "memory");
    __syncthreads();
    bf16x8 av[2];
    int rowA = wm * 16 + r15;
#pragma unroll
    for (int kh = 0; kh < 2; kh++) {
      int off = rowA * 128 + ((kh * 64 + hi) ^ ((rowA & 7) << 4));
      av[kh] = *(const bf16x8*)((const char*)lV + off);
    }
#pragma unroll
    for (int c = 0; c < 2; c++) {
      int rowB = (wn2 + c) * 16 + r15;
#pragma unroll
      for (int kh = 0; kh < 2; kh++) {
        int off = rowB * 128 + ((kh * 64 + hi) ^ ((rowB & 7) << 4));
        bf16x8 bu = *(const bf16x8*)((const char*)lU + off);
        accP[c] = MFMA(av[kh], bu, accP[c]);
      }
    }
    { int u = tid >> 2, partc = tid & 3;
#pragma unroll
      for (int h = 0; h < 2; h++) {
        int off = u * 128 + ((partc * 32 + h * 16) ^ ((u & 7) << 4));
        bf16x8 vv = *(const bf16x8*)((const char*)lU + off);
#pragma unroll
        for (int e = 0; e < 8; e++) c1p += bf2f(vv[e]);
      }
    }
    __syncthreads();
  }
  cpart[tid] = c1p;
#pragma unroll
  for (int c = 0; c < 2; c++)
#pragma unroll
    for (int j = 0; j < 4; j++) {
      int d = wm * 16 + g4 + j, u = (wn2 + c) * 16 + r15;
      GTl[d * 72 + u] = f2bf(accP[c][j]);
    }
  __syncthreads();
  if (tid < 64) cl[tid] = cpart[4 * tid] + cpart[4 * tid + 1] + cpart[4 * tid + 2] + cpart[4 * tid + 3];
  __syncthreads();

  bf16x8 gtb[2][2];
#pragma unroll
  for (int nt = 0; nt < 2; nt++)
#pragma unroll
    for (int kh = 0; kh < 2; kh++)
      gtb[nt][kh] = *(const bf16x8*)((const char*)GTl + (nt * 16 + r15) * 144 + kh * 64 + hi);

  float c1r[2][8];
#pragma unroll
  for (int kh = 0; kh < 2; kh++)
#pragma unroll
    for (int e = 0; e < 8; e++) c1r[kh][e] = cl[kh * 32 + g8 + e];

  const short* ibase = corrI + (size_t)bht * HW * 64;
  for (int s = 0; s < 16; s++) {
    int i0 = w * 256 + s * 16;
    bf16x8 af[2];
#pragma unroll
    for (int kh = 0; kh < 2; kh++)
      af[kh] = *(const bf16x8*)(ibase + (size_t)(i0 + r15) * 64 + kh * 32 + g8);
    f32x4 a2[2];
    a2[0] = (f32x4)0.f; a2[1] = (f32x4)0.f;
#pragma unroll
    for (int nt = 0; nt < 2; nt++)
#pragma unroll
      for (int kh = 0; kh < 2; kh++) a2[nt] = MFMA(af[kh], gtb[nt][kh], a2[nt]);

    float dp = 0.f;
#pragma unroll
    for (int kh = 0; kh < 2; kh++)
#pragma unroll
      for (int e = 0; e < 8; e++) dp += bf2f(af[kh][e]) * c1r[kh][e];
    dp += __shfl_xor(dp, 16);
    dp += __shfl_xor(dp, 32);

#pragma unroll
    for (int j = 0; j < 4; j++) {
      float dj = __shfl(dp, g4 + j);
      float inv = 1.f / dj;
      int i = i0 + g4 + j;
      size_t outrow = ((size_t)(g * HW + i)) * 512 + head * 64 + dh * 32;
#pragma unroll
      for (int nt = 0; nt < 2; nt++)
        out_attn[outrow + nt * 16 + r15] = f2bf(a2[nt][j] * inv);
    }
  }
}

extern "C" void kernel_launch(void* const* d_in, const int* in_sizes, int n_in,
                              void* d_out, int out_size, void* d_ws, size_t ws_size,
                              hipStream_t stream) {
  (void)in_sizes; (void)n_in; (void)out_size; (void)ws_size;
  const float* x      = (const float*)d_in[0];
  const float* w_qkv  = (const float*)d_in[1];
  const float* w_proj = (const float*)d_in[2];
  const float* b_proj = (const float*)d_in[3];

  char* ws = (char*)d_ws;
  short* qkvb   = (short*)(ws);                 // 50,331,648 B [16384][1536]
  short* xb     = (short*)(ws + 50331648);      // 16,777,216 B
  short* corrU  = (short*)(ws + 67108864);      // 16,777,216 B [128][64][1024]
  short* vT     = (short*)(ws + 83886080);      // 16,777,216 B [128][64][1024]
  short* wqkvb  = (short*)(ws + 100663296);     //  1,572,864 B
  short* wprojb = (short*)(ws + 102236160);     //    524,288 B
  short* corrI    = xb;    // alias: xb dead after qkv GEMM
  short* out_attn = qkvb;  // alias: qkvb dead after corr (incl. vT epilogue)

  k_cvt3<<<dim3(4608), 256, 0, stream>>>(x, w_qkv, w_proj, xb, wqkvb, wprojb);

  k_gemm_bt<0><<<dim3(1536), 256, 0, stream>>>(xb, wqkvb, qkvb, nullptr, 16384, 1536, 512);

  k_corr<<<dim3(2048), 512, 0, stream>>>(qkvb, corrI, corrU, vT);

  k_attn<<<dim3(256), 256, 0, stream>>>(corrU, corrI, vT, out_attn);

  k_gemm_bt<1><<<dim3(512), 256, 0, stream>>>(out_attn, wprojb, d_out, b_proj, 16384, 512, 512);
}